// Round 9
// baseline (70.315 us; speedup 1.0000x reference)
//
#include <hip/hip_runtime.h>

// Problem constants (fixed by reference setup_inputs()).
#define BB 8
#define CC 256
#define EE 18000
#define TT 4500
#define BT (BB * TT)     // 36000
#define BE (BB * EE)     // 144000
#define NT 512           // pool threads (8 waves)
#define W  36            // elements per window; stride 36 words = 144 B (16B-aligned,
                         // 36 mod 32 = 4 -> b128 accesses are bank-conflict-free)
#define PW (NT * W)      // 18432 floats = 73728 B -> 2 blocks/CU

// ---------------- setup ----------------------------------------------------

__global__ void zero_counts_kernel(int* __restrict__ counts) {
    int i = blockIdx.x * blockDim.x + threadIdx.x;
    if (i < BT) counts[i] = 0;
}

__global__ void count_kernel(const int* __restrict__ gid, int* __restrict__ counts) {
    int i = blockIdx.x * blockDim.x + threadIdx.x;
    if (i < BE) {
        int b = i / EE;
        atomicAdd(&counts[b * TT + gid[i]], 1);
    }
}

// one block per batch: exclusive scan of counts -> cursor (scatter cursor,
// base b*EE) and epilogue table tab[g] = {start | end<<16, bits(inv)}.
// No padding: raw CSR positions are the scan positions.
__global__ __launch_bounds__(1024) void scan_kernel(const int* __restrict__ counts,
                                                    int* __restrict__ cursor,
                                                    uint2* __restrict__ tab) {
    __shared__ int part[1024];
    const int b = blockIdx.x;
    const int t = threadIdx.x;
    const int CHUNK = 5;                          // 1024*5 >= 4500
    int lo = t * CHUNK; if (lo > TT) lo = TT;
    int hi = lo + CHUNK; if (hi > TT) hi = TT;
    int s = 0;
    for (int i = lo; i < hi; ++i) s += counts[b * TT + i];
    part[t] = s;
    __syncthreads();
    for (int d = 1; d < 1024; d <<= 1) {
        int v = (t >= d) ? part[t - d] : 0;
        __syncthreads();
        part[t] += v;
        __syncthreads();
    }
    int run = part[t] - s;                        // per-batch exclusive prefix
    for (int i = lo; i < hi; ++i) {
        int cnt = counts[b * TT + i];
        cursor[b * TT + i] = b * EE + run;
        int en = run + cnt;
        float inv = cnt ? 1.0f / (float)cnt : 0.0f;
        tab[b * TT + i] = make_uint2((unsigned)run | ((unsigned)en << 16),
                                     __float_as_uint(inv));
        run = en;
    }
}

// atomic CSR scatter: prank16[e] = raw CSR position of edge e in batch b
__global__ void scatter_kernel(const int* __restrict__ gid,
                               int* __restrict__ cursor,
                               unsigned short* __restrict__ prank16) {
    int i = blockIdx.x * blockDim.x + threadIdx.x;
    if (i < BE) {
        int b = i / EE;
        int p = atomicAdd(&cursor[b * TT + gid[i]], 1) - b * EE;
        prank16[i] = (unsigned short)p;           // < 18000
    }
}

// ---------------- main: scatter + vectorized block scan + epilogue ---------
// One block per (b,c), 512 threads, 73.8 KB LDS -> 2 blocks/CU (16 waves).
// Phase A: 9x ds_read_b128 per thread (conflict-free); intra-vec prefixes +
// 9-chunk offset chain. Phase C: 9x ds_write_b128. Epilogue: one 8B table
// load per group, Pa = end?P[end-1]:0, Pb = start?P[start-1]:0 (empty groups
// zero automatically). Threads >= 500 scan garbage windows (>= 18000): their
// results land in vals[18000..18432) / wsum[7], never consumed.

__global__ __launch_bounds__(512, 4) void pool_kernel(const float* __restrict__ fe,
                                                      const unsigned short* __restrict__ prank16,
                                                      const uint2* __restrict__ tab,
                                                      float* __restrict__ out) {
    __shared__ float vals[PW];                    // 73728 B
    __shared__ float wsum[8];
    const int b   = blockIdx.x >> 8;              // CC == 256
    const int c   = blockIdx.x & 255;
    const int tid = threadIdx.x;
    const int wv  = tid >> 6;
    const int ln  = tid & 63;

    // scatter row into CSR order (coalesced float4 + ushort4 reads)
    const float4*  fe4 = (const float4*)(fe + (size_t)(b * CC + c) * EE);
    const ushort4* rk4 = (const ushort4*)(prank16 + (size_t)b * EE);
#pragma unroll
    for (int i = 0; i < 9; ++i) {                 // 9*512 = 4608 >= 4500
        int idx = tid + (i << 9);
        if (idx < EE / 4) {
            float4  v = fe4[idx];
            ushort4 r = rk4[idx];
            vals[r.x] = v.x;
            vals[r.y] = v.y;
            vals[r.z] = v.z;
            vals[r.w] = v.w;
        }
    }
    __syncthreads();

    // phase A: 9x b128 loads; intra-vec inclusive prefixes; chunk sums
    const int base = W * tid;
    float4 pv[9];
    float  csum[9];
#pragma unroll
    for (int k = 0; k < 9; ++k) {
        float4 v = *reinterpret_cast<float4*>(&vals[base + (k << 2)]);
        float p0 = v.x;
        float p1 = p0 + v.y;
        float p2 = p1 + v.z;
        float p3 = p2 + v.w;
        pv[k] = make_float4(p0, p1, p2, p3);
        csum[k] = p3;
    }
    // window total via tree
    float t01 = csum[0] + csum[1], t23 = csum[2] + csum[3];
    float t45 = csum[4] + csum[5], t67 = csum[6] + csum[7];
    const float sum = ((t01 + t23) + (t45 + t67)) + csum[8];

    // per-wave inclusive shfl scan of window sums
    float sc = sum;
#pragma unroll
    for (int d = 1; d < 64; d <<= 1) {
        float o = __shfl_up(sc, d, 64);
        if (ln >= d) sc += o;
    }
    if (ln == 63) wsum[wv] = sc;                  // wave total
    __syncthreads();

    // cross-wave exclusive offset
    float cross = 0.0f;
#pragma unroll
    for (int j = 0; j < 8; ++j) {
        float tw = wsum[j];                       // broadcast read
        if (j < wv) cross += tw;
    }

    // phase C: add running offset, 9x b128 stores
    float off = cross + (sc - sum);               // exclusive prefix of window
#pragma unroll
    for (int k = 0; k < 9; ++k) {
        float4 p = pv[k];
        float4 o = make_float4(p.x + off, p.y + off, p.z + off, p.w + off);
        *reinterpret_cast<float4*>(&vals[base + (k << 2)]) = o;
        off += csum[k];
    }
    __syncthreads();

    // epilogue: one 8B table load per group; coalesced stores
    const uint2* tb   = tab + b * TT;
    float*       outb = out + (size_t)(b * CC + c) * TT;
#pragma unroll
    for (int k = 0; k < 9; ++k) {                 // 9*512 = 4608 >= 4500
        int g = tid + (k << 9);
        if (g < TT) {
            uint2 q = tb[g];
            unsigned int st = q.x & 0xffffu;
            unsigned int en = q.x >> 16;
            float Pa = en ? vals[en - 1] : 0.0f;
            float Pb = st ? vals[st - 1] : 0.0f;
            outb[g] = (Pa - Pb) * __uint_as_float(q.y);
        }
    }
}

extern "C" void kernel_launch(void* const* d_in, const int* in_sizes, int n_in,
                              void* d_out, int out_size, void* d_ws, size_t ws_size,
                              hipStream_t stream) {
    const float* fe  = (const float*)d_in[0];
    const int*   gid = (const int*)d_in[1];
    float*       out = (float*)d_out;

    // ws: counts[BT] i32 | cursor[BT] i32 | tab[BT] uint2 | prank16[BE] u16
    int*            counts  = (int*)d_ws;
    int*            cursor  = counts + BT;
    uint2*          tab     = (uint2*)(cursor + BT);
    unsigned short* prank16 = (unsigned short*)(tab + BT);

    zero_counts_kernel<<<(BT + 255) / 256, 256, 0, stream>>>(counts);
    count_kernel<<<(BE + 255) / 256, 256, 0, stream>>>(gid, counts);
    scan_kernel<<<BB, 1024, 0, stream>>>(counts, cursor, tab);
    scatter_kernel<<<(BE + 255) / 256, 256, 0, stream>>>(gid, cursor, prank16);
    pool_kernel<<<BB * CC, 512, 0, stream>>>(fe, prank16, tab, out);
}

// Round 11
// 62.798 us; speedup vs baseline: 1.1197x; 1.1197x over previous
//
#include <hip/hip_runtime.h>

// Problem constants (fixed by reference setup_inputs()).
#define BB 8
#define CC 256
#define EE 18000
#define TT 4500
#define BT (BB * TT)     // 36000
#define BE (BB * EE)     // 144000
#define NT 1024          // pool threads (16 waves) -> 2 blocks/CU = 32 waves/CU
#define W  18            // elements per window; stride 72 B (8B-aligned -> b64 vectors)
#define PW (NT * W)      // 18432 floats = 73728 B

// ---------------- setup ----------------------------------------------------

__global__ void zero_counts_kernel(int* __restrict__ counts) {
    int i = blockIdx.x * blockDim.x + threadIdx.x;
    if (i < BT) counts[i] = 0;
}

__global__ void count_kernel(const int* __restrict__ gid, int* __restrict__ counts) {
    int i = blockIdx.x * blockDim.x + threadIdx.x;
    if (i < BE) {
        int b = i / EE;
        atomicAdd(&counts[b * TT + gid[i]], 1);
    }
}

// one block per batch: exclusive scan of counts -> cursor (scatter cursor,
// base b*EE) and epilogue table tab[g] = {start | end<<16, bits(inv)}.
__global__ __launch_bounds__(1024) void scan_kernel(const int* __restrict__ counts,
                                                    int* __restrict__ cursor,
                                                    uint2* __restrict__ tab) {
    __shared__ int part[1024];
    const int b = blockIdx.x;
    const int t = threadIdx.x;
    const int CHUNK = 5;                          // 1024*5 >= 4500
    int lo = t * CHUNK; if (lo > TT) lo = TT;
    int hi = lo + CHUNK; if (hi > TT) hi = TT;
    int s = 0;
    for (int i = lo; i < hi; ++i) s += counts[b * TT + i];
    part[t] = s;
    __syncthreads();
    for (int d = 1; d < 1024; d <<= 1) {
        int v = (t >= d) ? part[t - d] : 0;
        __syncthreads();
        part[t] += v;
        __syncthreads();
    }
    int run = part[t] - s;                        // per-batch exclusive prefix
    for (int i = lo; i < hi; ++i) {
        int cnt = counts[b * TT + i];
        cursor[b * TT + i] = b * EE + run;
        int en = run + cnt;
        float inv = cnt ? 1.0f / (float)cnt : 0.0f;
        tab[b * TT + i] = make_uint2((unsigned)run | ((unsigned)en << 16),
                                     __float_as_uint(inv));
        run = en;
    }
}

// atomic CSR scatter: prank16[e] = raw CSR position of edge e in batch b
__global__ void scatter_kernel(const int* __restrict__ gid,
                               int* __restrict__ cursor,
                               unsigned short* __restrict__ prank16) {
    int i = blockIdx.x * blockDim.x + threadIdx.x;
    if (i < BE) {
        int b = i / EE;
        int p = atomicAdd(&cursor[b * TT + gid[i]], 1) - b * EE;
        prank16[i] = (unsigned short)p;           // < 18000
    }
}

// ---------------- main: scatter + vectorized block scan + epilogue ---------
// One block per (b,c), 1024 threads, 73.8 KB LDS -> 2 blocks/CU = 32 waves.
// Phase A: 9x ds_read_b64 per thread; Phase C: 9x ds_write_b64. Epilogue:
// grid-stride over 1125 quad-slots (fixes R10's tid<1125 vs 1024-thread bug):
// 2x uint4 tab load, 5 chained LDS gathers (st(g+1)==en(g)), 1x float4 store.
// Windows >= 1000 are garbage but pollute only wsum[15] (never consumed) and
// vals[18000..18432) (never read).

__global__ __launch_bounds__(1024, 8) void pool_kernel(const float* __restrict__ fe,
                                                       const unsigned short* __restrict__ prank16,
                                                       const uint2* __restrict__ tab,
                                                       float* __restrict__ out) {
    __shared__ float vals[PW];                    // 73728 B
    __shared__ float wsum[16];
    const int b   = blockIdx.x >> 8;              // CC == 256
    const int c   = blockIdx.x & 255;
    const int tid = threadIdx.x;
    const int wv  = tid >> 6;
    const int ln  = tid & 63;

    // scatter row into CSR order (coalesced float4 + ushort4 reads)
    const float4*  fe4 = (const float4*)(fe + (size_t)(b * CC + c) * EE);
    const ushort4* rk4 = (const ushort4*)(prank16 + (size_t)b * EE);
#pragma unroll
    for (int i = 0; i < 5; ++i) {                 // 5*1024 = 5120 >= 4500
        int idx = tid + (i << 10);
        if (idx < EE / 4) {
            float4  v = fe4[idx];
            ushort4 r = rk4[idx];
            vals[r.x] = v.x;
            vals[r.y] = v.y;
            vals[r.z] = v.z;
            vals[r.w] = v.w;
        }
    }
    __syncthreads();

    // phase A: 9x b64 loads; intra-vec prefixes; chunk sums
    const int base = W * tid;
    float2 pv[9];
    float  csum[9];
#pragma unroll
    for (int k = 0; k < 9; ++k) {
        float2 v = *reinterpret_cast<const float2*>(&vals[base + (k << 1)]);
        float p0 = v.x;
        float p1 = p0 + v.y;
        pv[k] = make_float2(p0, p1);
        csum[k] = p1;
    }
    float t01 = csum[0] + csum[1], t23 = csum[2] + csum[3];
    float t45 = csum[4] + csum[5], t67 = csum[6] + csum[7];
    const float sum = ((t01 + t23) + (t45 + t67)) + csum[8];

    // per-wave inclusive shfl scan of window sums
    float sc = sum;
#pragma unroll
    for (int d = 1; d < 64; d <<= 1) {
        float o = __shfl_up(sc, d, 64);
        if (ln >= d) sc += o;
    }
    if (ln == 63) wsum[wv] = sc;                  // wave total
    __syncthreads();

    // cross-wave exclusive offset
    float cross = 0.0f;
#pragma unroll
    for (int j = 0; j < 16; ++j) {
        float tw = wsum[j];                       // broadcast read
        if (j < wv) cross += tw;
    }

    // phase C: add running offset, 9x b64 stores
    float off = cross + (sc - sum);               // exclusive prefix of window
#pragma unroll
    for (int k = 0; k < 9; ++k) {
        float2 p = pv[k];
        *reinterpret_cast<float2*>(&vals[base + (k << 1)]) =
            make_float2(p.x + off, p.y + off);
        off += csum[k];
    }
    __syncthreads();

    // epilogue: 4 consecutive groups per slot; 1125 slots, grid-stride
    const uint2* tbB  = tab + b * TT;
    float*       outb = out + (size_t)(b * CC + c) * TT;
    for (int s = tid; s < TT / 4; s += NT) {      // 1125 slots / 1024 threads
        const uint2* tb = tbB + (s << 2);
        uint4 qA = *reinterpret_cast<const uint4*>(tb);      // groups 4s,4s+1
        uint4 qB = *reinterpret_cast<const uint4*>(tb + 2);  // groups 4s+2,4s+3

        unsigned se0 = qA.x, se1 = qA.z, se2 = qB.x, se3 = qB.z;
        float iv0 = __uint_as_float(qA.y), iv1 = __uint_as_float(qA.w);
        float iv2 = __uint_as_float(qB.y), iv3 = __uint_as_float(qB.w);

        unsigned st0 = se0 & 0xffffu;
        unsigned en0 = se0 >> 16, en1 = se1 >> 16, en2 = se2 >> 16, en3 = se3 >> 16;

        // P(pos) = pos ? vals[pos-1] : 0; all reads clamped to valid range
        float Pp = vals[(st0 ? st0 : 1u) - 1u]; Pp = st0 ? Pp : 0.0f;
        float P0 = vals[(en0 ? en0 : 1u) - 1u]; P0 = en0 ? P0 : 0.0f;
        float P1 = vals[(en1 ? en1 : 1u) - 1u]; P1 = en1 ? P1 : 0.0f;
        float P2 = vals[(en2 ? en2 : 1u) - 1u]; P2 = en2 ? P2 : 0.0f;
        float P3 = vals[(en3 ? en3 : 1u) - 1u]; P3 = en3 ? P3 : 0.0f;

        float4 o;
        o.x = (P0 - Pp) * iv0;                    // st(g+1) == en(g): chain
        o.y = (P1 - P0) * iv1;
        o.z = (P2 - P1) * iv2;
        o.w = (P3 - P2) * iv3;

        *reinterpret_cast<float4*>(outb + (s << 2)) = o;
    }
}

extern "C" void kernel_launch(void* const* d_in, const int* in_sizes, int n_in,
                              void* d_out, int out_size, void* d_ws, size_t ws_size,
                              hipStream_t stream) {
    const float* fe  = (const float*)d_in[0];
    const int*   gid = (const int*)d_in[1];
    float*       out = (float*)d_out;

    // ws: counts[BT] i32 | cursor[BT] i32 | tab[BT] uint2 | prank16[BE] u16
    int*            counts  = (int*)d_ws;
    int*            cursor  = counts + BT;
    uint2*          tab     = (uint2*)(cursor + BT);   // byte offset 288000, 16B-aligned
    unsigned short* prank16 = (unsigned short*)(tab + BT);

    zero_counts_kernel<<<(BT + 255) / 256, 256, 0, stream>>>(counts);
    count_kernel<<<(BE + 255) / 256, 256, 0, stream>>>(gid, counts);
    scan_kernel<<<BB, 1024, 0, stream>>>(counts, cursor, tab);
    scatter_kernel<<<(BE + 255) / 256, 256, 0, stream>>>(gid, cursor, prank16);
    pool_kernel<<<BB * CC, 1024, 0, stream>>>(fe, prank16, tab, out);
}